// Round 1
// baseline (545.198 us; speedup 1.0000x reference)
//
#include <hip/hip_runtime.h>
#include <stdint.h>

#define BDIM 64
#define SDIM 1024
#define EDIM 512
#define ADIM 128
#define M_ROWS (BDIM*(SDIM-1))   // 65472
#define KDIM 1024                // 2E
#define NDIM 1024                // 2E

typedef unsigned short u16;
typedef __attribute__((ext_vector_type(8))) short short8;
typedef __attribute__((ext_vector_type(4))) float floatx4;
typedef const __attribute__((address_space(1))) void as1_void;
typedef __attribute__((address_space(3))) void as3_void;

__device__ inline u16 f2bf(float f){
  unsigned int u = __float_as_uint(f);
  u += 0x7fffu + ((u >> 16) & 1u);
  return (u16)(u >> 16);
}

// ---------------- cast states fp32 -> bf16 (8 elems/thread/iter) ----------------
__global__ void k_cast_states(const float* __restrict__ src, u16* __restrict__ dst, int n8){
  int i = blockIdx.x*blockDim.x + threadIdx.x;
  int stride = gridDim.x*blockDim.x;
  for (; i < n8; i += stride){
    const float4* s = (const float4*)src + (size_t)i*2;
    float4 a = s[0], b = s[1];
    short8 v;
    v[0]=(short)f2bf(a.x); v[1]=(short)f2bf(a.y); v[2]=(short)f2bf(a.z); v[3]=(short)f2bf(a.w);
    v[4]=(short)f2bf(b.x); v[5]=(short)f2bf(b.y); v[6]=(short)f2bf(b.z); v[7]=(short)f2bf(b.w);
    ((short8*)dst)[i] = v;
  }
}

// ---------------- transpose+cast W1p (K x N) -> Wt (N x K) bf16 ----------------
__global__ void k_transpose_w1p(const float* __restrict__ w, u16* __restrict__ wt){
  __shared__ float tile[32][33];
  int k0 = blockIdx.x*32, n0 = blockIdx.y*32;
  int tx = threadIdx.x, ty = threadIdx.y;
  for (int j = ty; j < 32; j += 8) tile[j][tx] = w[(k0+j)*NDIM + n0 + tx];
  __syncthreads();
  for (int j = ty; j < 32; j += 8) wt[(n0+j)*KDIM + k0 + tx] = f2bf(tile[tx][j]);
}

__global__ void k_zero_scores(float* __restrict__ s){
  int i = blockIdx.x*blockDim.x + threadIdx.x;
  if (i < M_ROWS) s[i] = 0.f;
}

// ---------------- main GEMM: scores[m] += sum_n relu(x_m.W1p + b1p)[n]*w2p[n] ----------------
// A row m=(b,s): 1024 contiguous bf16 at states_bf16 + (b*1024+s)*512.
// LDS layout: 16B granules, granule g holds (row m=g>>3, chunk c=(g&7)^(m&7)) of the BKx? tile.
__global__ __launch_bounds__(256, 2) void k_gemm_scores(
    const u16* __restrict__ sbf, const u16* __restrict__ wt,
    const float* __restrict__ b1p, const float* __restrict__ w2p,
    float* __restrict__ scores)
{
  __shared__ short8 Ash[1024];   // 128 rows x 64 k (bf16) = 16 KB
  __shared__ short8 Bsh[1024];   // 128 n    x 64 k (bf16) = 16 KB
  const int tid = threadIdx.x;
  const int w = tid >> 6, l = tid & 63;
  const int mt = blockIdx.x, nt = blockIdx.y;

  // -------- staging addresses (per-lane) --------
  const int lrow8 = l >> 3;            // 0..7 : row within 8-row group
  const int c = (l & 7) ^ lrow8;       // swizzled chunk this lane fetches
  const char* sbase = (const char*)sbf;
  const char* wbase = (const char*)wt;
  int offA[4], offB[4];
#pragma unroll
  for (int i = 0; i < 4; ++i){
    int mloc = (w*4 + i)*8 + lrow8;          // tile-local row 0..127
    int mg = mt*128 + mloc;
    if (mg >= M_ROWS) mg = 0;                // clamp; epilogue skips OOB rows
    int bb = mg / 1023;
    int ss = mg - bb*1023;
    offA[i] = bb*1048576 + ss*1024 + c*16;   // byte offset of (row, chunk c) at kt=0
    int nloc = (w*4 + i)*8 + lrow8;
    offB[i] = (nt*128 + nloc)*2048 + c*16;   // Wt row stride = 1024 bf16 = 2048 B
  }

  // -------- fragment read indices --------
  const int r = l & 15, q = l >> 4;
  const int wm = w & 1, wn = w >> 1;         // 2x2 wave grid, each 64x64
  int aIdx[4], bIdx[4];
#pragma unroll
  for (int i = 0; i < 4; ++i){
    int m = wm*64 + i*16 + r;
    aIdx[i] = m*8 + (q ^ (r & 7));
    int n = wn*64 + i*16 + r;
    bIdx[i] = n*8 + (q ^ (r & 7));
  }

  floatx4 acc[4][4];
#pragma unroll
  for (int a = 0; a < 4; ++a)
#pragma unroll
    for (int b = 0; b < 4; ++b) acc[a][b] = (floatx4)(0.0f);

  for (int step = 0; step < 16; ++step){
    const int ktb = step * 128;              // kt*2 bytes (kt = step*64 bf16)
    __syncthreads();                          // prev tile's reads complete
#pragma unroll
    for (int i = 0; i < 4; ++i){
      __builtin_amdgcn_global_load_lds((as1_void*)(sbase + offA[i] + ktb),
                                       (as3_void*)((char*)Ash + (w*4 + i)*1024), 16, 0, 0);
    }
#pragma unroll
    for (int i = 0; i < 4; ++i){
      __builtin_amdgcn_global_load_lds((as1_void*)(wbase + offB[i] + ktb),
                                       (as3_void*)((char*)Bsh + (w*4 + i)*1024), 16, 0, 0);
    }
    __syncthreads();                          // staging visible (vmcnt drain)
#pragma unroll
    for (int kh = 0; kh < 2; ++kh){
      short8 af[4], bf[4];
#pragma unroll
      for (int i = 0; i < 4; ++i) af[i] = Ash[aIdx[i] ^ (kh*4)];
#pragma unroll
      for (int i = 0; i < 4; ++i) bf[i] = Bsh[bIdx[i] ^ (kh*4)];
#pragma unroll
      for (int mi = 0; mi < 4; ++mi)
#pragma unroll
        for (int ni = 0; ni < 4; ++ni)
          acc[mi][ni] = __builtin_amdgcn_mfma_f32_16x16x32_bf16(af[mi], bf[ni], acc[mi][ni], 0, 0, 0);
    }
  }

  // -------- fused epilogue: relu(h + b1p)*w2p, reduce over n, atomic into scores --------
  const int mrow0 = mt*128 + wm*64;
  const int ncol0 = nt*128 + wn*64;
#pragma unroll
  for (int mi = 0; mi < 4; ++mi){
    float t0 = 0.f, t1 = 0.f, t2 = 0.f, t3 = 0.f;
#pragma unroll
    for (int ni = 0; ni < 4; ++ni){
      int n = ncol0 + ni*16 + r;
      float bb = b1p[n], ww = w2p[n];
      floatx4 a = acc[mi][ni];
      t0 += fmaxf(a[0] + bb, 0.f) * ww;
      t1 += fmaxf(a[1] + bb, 0.f) * ww;
      t2 += fmaxf(a[2] + bb, 0.f) * ww;
      t3 += fmaxf(a[3] + bb, 0.f) * ww;
    }
#pragma unroll
    for (int off = 1; off < 16; off <<= 1){
      t0 += __shfl_xor(t0, off);
      t1 += __shfl_xor(t1, off);
      t2 += __shfl_xor(t2, off);
      t3 += __shfl_xor(t3, off);
    }
    if (r == 0){
      int row = mrow0 + mi*16 + q*4;
      if (row + 0 < M_ROWS) atomicAdd(&scores[row + 0], t0);
      if (row + 1 < M_ROWS) atomicAdd(&scores[row + 1], t1);
      if (row + 2 < M_ROWS) atomicAdd(&scores[row + 2], t2);
      if (row + 3 < M_ROWS) atomicAdd(&scores[row + 3], t3);
    }
  }
}

// ---------------- masked log-softmax over positions: logp_pos, ent_pos ----------------
__global__ void k_pos_head(const float* __restrict__ scores, const int* __restrict__ lengths,
                           const int* __restrict__ pos_action, float* __restrict__ out){
  __shared__ float red[8];
  int b = blockIdx.x, tid = threadIdx.x;
  const float* sc = scores + b*(SDIM-1);
  int L = lengths[b] - 1;
  float mx = -1e30f;
  for (int s = tid; s < L; s += 256) mx = fmaxf(mx, sc[s]);
  for (int off = 32; off; off >>= 1) mx = fmaxf(mx, __shfl_xor(mx, off));
  if ((tid & 63) == 0) red[tid >> 6] = mx;
  __syncthreads();
  mx = fmaxf(fmaxf(red[0], red[1]), fmaxf(red[2], red[3]));
  float se = 0.f, ses = 0.f;
  for (int s = tid; s < L; s += 256){
    float v = sc[s];
    float e = expf(v - mx);
    se += e; ses += e * v;
  }
  for (int off = 32; off; off >>= 1){ se += __shfl_xor(se, off); ses += __shfl_xor(ses, off); }
  __syncthreads();
  if ((tid & 63) == 0){ red[tid >> 6] = se; red[4 + (tid >> 6)] = ses; }
  __syncthreads();
  if (tid == 0){
    float S = red[0] + red[1] + red[2] + red[3];
    float SS = red[4] + red[5] + red[6] + red[7];
    float logZ = logf(S);
    int pa = pos_action[b];
    out[b]       = sc[pa] - mx - logZ;      // logp_pos
    out[192 + b] = mx + logZ - SS / S;      // ent_pos
  }
}

// ---------------- symbol head (fp32, tiny): logp_sym, ent_sym ----------------
__global__ void k_symbol_head(const float* __restrict__ states, const float* __restrict__ W1s,
                              const float* __restrict__ b1s, const float* __restrict__ W2s,
                              const int* __restrict__ pos_action, const int* __restrict__ sym_action,
                              float* __restrict__ out){
  __shared__ float x[1024];
  __shared__ float sh[1024];
  __shared__ float lg[128];
  __shared__ float red[8];
  int b = blockIdx.x, tid = threadIdx.x;
  int pa = pos_action[b];
  const float* src = states + (size_t)(b*SDIM + pa) * EDIM;  // e1||e2 contiguous (1024 f32)
  for (int i = tid; i < 1024; i += 256) x[i] = src[i];
  __syncthreads();
  float a0 = b1s[tid], a1 = b1s[tid+256], a2 = b1s[tid+512], a3 = b1s[tid+768];
  for (int k = 0; k < 1024; ++k){
    float xv = x[k];
    const float* wr = W1s + (size_t)k * 1024;
    a0 = fmaf(xv, wr[tid],     a0);
    a1 = fmaf(xv, wr[tid+256], a1);
    a2 = fmaf(xv, wr[tid+512], a2);
    a3 = fmaf(xv, wr[tid+768], a3);
  }
  sh[tid]     = fmaxf(a0, 0.f);
  sh[tid+256] = fmaxf(a1, 0.f);
  sh[tid+512] = fmaxf(a2, 0.f);
  sh[tid+768] = fmaxf(a3, 0.f);
  __syncthreads();
  if (tid < 128){
    float acc = 0.f;
    for (int f = 0; f < 1024; ++f) acc = fmaf(sh[f], W2s[f*ADIM + tid], acc);
    lg[tid] = acc;   // b2s cancels in log_softmax
  }
  __syncthreads();
  float v = (tid < 128) ? lg[tid] : -1e30f;
  float mx = v;
  for (int off = 32; off; off >>= 1) mx = fmaxf(mx, __shfl_xor(mx, off));
  if ((tid & 63) == 0) red[tid >> 6] = mx;
  __syncthreads();
  mx = fmaxf(fmaxf(red[0], red[1]), fmaxf(red[2], red[3]));
  float e = (tid < 128) ? expf(v - mx) : 0.f;
  float se = e, ses = e * ((tid < 128) ? v : 0.f);
  for (int off = 32; off; off >>= 1){ se += __shfl_xor(se, off); ses += __shfl_xor(ses, off); }
  __syncthreads();
  if ((tid & 63) == 0){ red[tid >> 6] = se; red[4 + (tid >> 6)] = ses; }
  __syncthreads();
  if (tid == 0){
    float S = red[0] + red[1] + red[2] + red[3];
    float SS = red[4] + red[5] + red[6] + red[7];
    float logZ = logf(S);
    out[64 + b]  = lg[sym_action[b]] - mx - logZ;  // logp_sym
    out[256 + b] = mx + logZ - SS / S;             // ent_sym
  }
}

// ---------------- value head ----------------
__global__ void k_value_head(const float* __restrict__ cls, const float* __restrict__ Wc1,
                             const float* __restrict__ bc1, const float* __restrict__ wc2,
                             const float* __restrict__ bc2, float* __restrict__ out){
  __shared__ float x[512];
  __shared__ float red[4];
  int b = blockIdx.x, tid = threadIdx.x;
  for (int i = tid; i < 512; i += 256) x[i] = cls[b*EDIM + i];
  __syncthreads();
  float a0 = bc1[tid], a1 = bc1[tid + 256];
  for (int k = 0; k < 512; ++k){
    float xv = x[k];
    a0 = fmaf(xv, Wc1[k*EDIM + tid],       a0);
    a1 = fmaf(xv, Wc1[k*EDIM + tid + 256], a1);
  }
  float p = fmaxf(a0, 0.f) * wc2[tid] + fmaxf(a1, 0.f) * wc2[tid + 256];
  for (int off = 32; off; off >>= 1) p += __shfl_xor(p, off);
  if ((tid & 63) == 0) red[tid >> 6] = p;
  __syncthreads();
  if (tid == 0) out[128 + b] = red[0] + red[1] + red[2] + red[3] + bc2[0];  // val
}

extern "C" void kernel_launch(void* const* d_in, const int* in_sizes, int n_in,
                              void* d_out, int out_size, void* d_ws, size_t ws_size,
                              hipStream_t stream){
  const float* states = (const float*)d_in[0];
  const float* cls    = (const float*)d_in[1];
  const float* W1p    = (const float*)d_in[2];
  const float* b1p    = (const float*)d_in[3];
  const float* w2p    = (const float*)d_in[4];
  const float* W1s    = (const float*)d_in[6];
  const float* b1s    = (const float*)d_in[7];
  const float* W2s    = (const float*)d_in[8];
  const float* Wc1    = (const float*)d_in[10];
  const float* bc1    = (const float*)d_in[11];
  const float* wc2    = (const float*)d_in[12];
  const float* bc2    = (const float*)d_in[13];
  const int* lengths  = (const int*)d_in[14];
  const int* pos_a    = (const int*)d_in[15];
  const int* sym_a    = (const int*)d_in[16];
  float* out = (float*)d_out;

  char* ws = (char*)d_ws;
  u16* sbf      = (u16*)ws;                                  // 67108864 B (states bf16)
  u16* wt       = (u16*)(ws + 67108864);                     //  2097152 B (W1p^T bf16)
  float* scores = (float*)(ws + 67108864 + 2097152);         //   261888 B

  k_cast_states<<<4096, 256, 0, stream>>>(states, sbf, 4194304);
  k_transpose_w1p<<<dim3(32, 32), dim3(32, 8), 0, stream>>>(W1p, wt);
  k_zero_scores<<<256, 256, 0, stream>>>(scores);
  k_gemm_scores<<<dim3(512, 8), 256, 0, stream>>>(sbf, wt, b1p, w2p, scores);
  k_pos_head<<<64, 256, 0, stream>>>(scores, lengths, pos_a, out);
  k_symbol_head<<<64, 256, 0, stream>>>(states, W1s, b1s, W2s, pos_a, sym_a, out);
  k_value_head<<<64, 256, 0, stream>>>(cls, Wc1, bc1, wc2, bc2, out);
}

// Round 2
// 438.390 us; speedup vs baseline: 1.2436x; 1.2436x over previous
//
#include <hip/hip_runtime.h>
#include <stdint.h>

#define BDIM 64
#define SDIM 1024
#define EDIM 512
#define ADIM 128
#define M_ROWS (BDIM*(SDIM-1))   // 65472
#define KDIM 1024                // 2E
#define NDIM 1024                // 2E

typedef unsigned short u16;
typedef __attribute__((ext_vector_type(8))) short short8;
typedef __attribute__((ext_vector_type(4))) float floatx4;
typedef const __attribute__((address_space(1))) void as1_void;
typedef __attribute__((address_space(3))) void as3_void;

__device__ inline u16 f2bf(float f){
  unsigned int u = __float_as_uint(f);
  u += 0x7fffu + ((u >> 16) & 1u);
  return (u16)(u >> 16);
}

// ---------------- cast states fp32 -> bf16 (8 elems/thread/iter) ----------------
__global__ void k_cast_states(const float* __restrict__ src, u16* __restrict__ dst, int n8){
  int i = blockIdx.x*blockDim.x + threadIdx.x;
  int stride = gridDim.x*blockDim.x;
  for (; i < n8; i += stride){
    const float4* s = (const float4*)src + (size_t)i*2;
    float4 a = s[0], b = s[1];
    short8 v;
    v[0]=(short)f2bf(a.x); v[1]=(short)f2bf(a.y); v[2]=(short)f2bf(a.z); v[3]=(short)f2bf(a.w);
    v[4]=(short)f2bf(b.x); v[5]=(short)f2bf(b.y); v[6]=(short)f2bf(b.z); v[7]=(short)f2bf(b.w);
    ((short8*)dst)[i] = v;
  }
}

// ---------------- transpose+cast W1p (K x N) -> Wt (N x K) bf16 ----------------
__global__ void k_transpose_w1p(const float* __restrict__ w, u16* __restrict__ wt){
  __shared__ float tile[32][33];
  int k0 = blockIdx.x*32, n0 = blockIdx.y*32;
  int tx = threadIdx.x, ty = threadIdx.y;
  for (int j = ty; j < 32; j += 8) tile[j][tx] = w[(k0+j)*NDIM + n0 + tx];
  __syncthreads();
  for (int j = ty; j < 32; j += 8) wt[(n0+j)*KDIM + k0 + tx] = f2bf(tile[tx][j]);
}

__global__ void k_zero_scores(float* __restrict__ s){
  int i = blockIdx.x*blockDim.x + threadIdx.x;
  if (i < M_ROWS) s[i] = 0.f;
}

// ---------------- main GEMM: scores[m] += sum_n relu(x_m.W1p + b1p)[n]*w2p[n] ----------------
// grid = (nt=8, mt=512): nt fastest-varying so the 8 blocks sharing an A row-block
// dispatch adjacently -> A re-fetch served by L2/LLC instead of HBM.
__global__ __launch_bounds__(256, 2) void k_gemm_scores(
    const u16* __restrict__ sbf, const u16* __restrict__ wt,
    const float* __restrict__ b1p, const float* __restrict__ w2p,
    float* __restrict__ scores)
{
  __shared__ short8 Ash[1024];   // 128 rows x 64 k (bf16) = 16 KB
  __shared__ short8 Bsh[1024];   // 128 n    x 64 k (bf16) = 16 KB
  const int tid = threadIdx.x;
  const int w = tid >> 6, l = tid & 63;
  const int nt = blockIdx.x, mt = blockIdx.y;

  // -------- staging addresses (per-lane) --------
  const int lrow8 = l >> 3;            // 0..7 : row within 8-row group
  const int c = (l & 7) ^ lrow8;       // swizzled chunk this lane fetches
  const char* sbase = (const char*)sbf;
  const char* wbase = (const char*)wt;
  int offA[4], offB[4];
#pragma unroll
  for (int i = 0; i < 4; ++i){
    int mloc = (w*4 + i)*8 + lrow8;          // tile-local row 0..127
    int mg = mt*128 + mloc;
    if (mg >= M_ROWS) mg = 0;                // clamp; epilogue skips OOB rows
    int bb = mg / 1023;
    int ss = mg - bb*1023;
    offA[i] = bb*1048576 + ss*1024 + c*16;   // byte offset of (row, chunk c) at kt=0
    int nloc = (w*4 + i)*8 + lrow8;
    offB[i] = (nt*128 + nloc)*2048 + c*16;   // Wt row stride = 1024 bf16 = 2048 B
  }

  // -------- fragment read indices --------
  const int r = l & 15, q = l >> 4;
  const int wm = w & 1, wn = w >> 1;         // 2x2 wave grid, each 64x64
  int aIdx[4], bIdx[4];
#pragma unroll
  for (int i = 0; i < 4; ++i){
    int m = wm*64 + i*16 + r;
    aIdx[i] = m*8 + (q ^ (r & 7));
    int n = wn*64 + i*16 + r;
    bIdx[i] = n*8 + (q ^ (r & 7));
  }

  floatx4 acc[4][4];
#pragma unroll
  for (int a = 0; a < 4; ++a)
#pragma unroll
    for (int b = 0; b < 4; ++b) acc[a][b] = (floatx4)(0.0f);

  for (int step = 0; step < 16; ++step){
    const int ktb = step * 128;              // kt*2 bytes (kt = step*64 bf16)
    __syncthreads();                          // prev tile's reads complete
#pragma unroll
    for (int i = 0; i < 4; ++i){
      __builtin_amdgcn_global_load_lds((as1_void*)(sbase + offA[i] + ktb),
                                       (as3_void*)((char*)Ash + (w*4 + i)*1024), 16, 0, 0);
    }
#pragma unroll
    for (int i = 0; i < 4; ++i){
      __builtin_amdgcn_global_load_lds((as1_void*)(wbase + offB[i] + ktb),
                                       (as3_void*)((char*)Bsh + (w*4 + i)*1024), 16, 0, 0);
    }
    __syncthreads();                          // staging visible (vmcnt drain)
#pragma unroll
    for (int kh = 0; kh < 2; ++kh){
      short8 af[4], bf[4];
#pragma unroll
      for (int i = 0; i < 4; ++i) af[i] = Ash[aIdx[i] ^ (kh*4)];
#pragma unroll
      for (int i = 0; i < 4; ++i) bf[i] = Bsh[bIdx[i] ^ (kh*4)];
#pragma unroll
      for (int mi = 0; mi < 4; ++mi)
#pragma unroll
        for (int ni = 0; ni < 4; ++ni)
          acc[mi][ni] = __builtin_amdgcn_mfma_f32_16x16x32_bf16(af[mi], bf[ni], acc[mi][ni], 0, 0, 0);
    }
  }

  // -------- fused epilogue: relu(h + b1p)*w2p, reduce over n, atomic into scores --------
  const int mrow0 = mt*128 + wm*64;
  const int ncol0 = nt*128 + wn*64;
#pragma unroll
  for (int mi = 0; mi < 4; ++mi){
    float t0 = 0.f, t1 = 0.f, t2 = 0.f, t3 = 0.f;
#pragma unroll
    for (int ni = 0; ni < 4; ++ni){
      int n = ncol0 + ni*16 + r;
      float bb = b1p[n], ww = w2p[n];
      floatx4 a = acc[mi][ni];
      t0 += fmaxf(a[0] + bb, 0.f) * ww;
      t1 += fmaxf(a[1] + bb, 0.f) * ww;
      t2 += fmaxf(a[2] + bb, 0.f) * ww;
      t3 += fmaxf(a[3] + bb, 0.f) * ww;
    }
#pragma unroll
    for (int off = 1; off < 16; off <<= 1){
      t0 += __shfl_xor(t0, off);
      t1 += __shfl_xor(t1, off);
      t2 += __shfl_xor(t2, off);
      t3 += __shfl_xor(t3, off);
    }
    if (r == 0){
      int row = mrow0 + mi*16 + q*4;
      if (row + 0 < M_ROWS) atomicAdd(&scores[row + 0], t0);
      if (row + 1 < M_ROWS) atomicAdd(&scores[row + 1], t1);
      if (row + 2 < M_ROWS) atomicAdd(&scores[row + 2], t2);
      if (row + 3 < M_ROWS) atomicAdd(&scores[row + 3], t3);
    }
  }
}

// ---------------- masked log-softmax over positions: logp_pos, ent_pos ----------------
__global__ void k_pos_head(const float* __restrict__ scores, const int* __restrict__ lengths,
                           const int* __restrict__ pos_action, float* __restrict__ out){
  __shared__ float red[8];
  int b = blockIdx.x, tid = threadIdx.x;
  const float* sc = scores + b*(SDIM-1);
  int L = lengths[b] - 1;
  float mx = -1e30f;
  for (int s = tid; s < L; s += 256) mx = fmaxf(mx, sc[s]);
  for (int off = 32; off; off >>= 1) mx = fmaxf(mx, __shfl_xor(mx, off));
  if ((tid & 63) == 0) red[tid >> 6] = mx;
  __syncthreads();
  mx = fmaxf(fmaxf(red[0], red[1]), fmaxf(red[2], red[3]));
  float se = 0.f, ses = 0.f;
  for (int s = tid; s < L; s += 256){
    float v = sc[s];
    float e = expf(v - mx);
    se += e; ses += e * v;
  }
  for (int off = 32; off; off >>= 1){ se += __shfl_xor(se, off); ses += __shfl_xor(ses, off); }
  __syncthreads();
  if ((tid & 63) == 0){ red[tid >> 6] = se; red[4 + (tid >> 6)] = ses; }
  __syncthreads();
  if (tid == 0){
    float S = red[0] + red[1] + red[2] + red[3];
    float SS = red[4] + red[5] + red[6] + red[7];
    float logZ = logf(S);
    int pa = pos_action[b];
    out[b]       = sc[pa] - mx - logZ;      // logp_pos
    out[192 + b] = mx + logZ - SS / S;      // ent_pos
  }
}

// ---------------- symbol head stage 1: sh[b][n] = relu(x_b . W1s[:,n] + b1s[n]) ----------------
// grid (4 nchunk, 64 b) x 1024 thr: n = n0 + (tid&255), k-quarter = tid>>8 (256 iters)
__global__ __launch_bounds__(1024) void k_sym_h(
    const float* __restrict__ states, const float* __restrict__ W1s,
    const float* __restrict__ b1s, const int* __restrict__ pos_action,
    float* __restrict__ sh)
{
  __shared__ float xs[1024];
  __shared__ float red[1024];
  int b = blockIdx.y, tid = threadIdx.x;
  int n0 = blockIdx.x * 256;
  int pa = pos_action[b];
  const float* src = states + (size_t)(b*SDIM + pa) * EDIM;  // e1||e2 contiguous
  xs[tid] = src[tid];
  __syncthreads();
  int n = n0 + (tid & 255);
  int k0 = (tid >> 8) * 256;
  float acc = 0.f;
#pragma unroll 8
  for (int j = 0; j < 256; ++j){
    int k = k0 + j;
    acc = fmaf(xs[k], W1s[(size_t)k*1024 + n], acc);
  }
  red[tid] = acc;
  __syncthreads();
  if (tid < 256){
    float s = red[tid] + red[tid+256] + red[tid+512] + red[tid+768];
    sh[b*1024 + n0 + tid] = fmaxf(s + b1s[n0 + tid], 0.f);
  }
}

// ---------------- symbol head stage 2: logits + log-softmax -> logp_sym, ent_sym ----------------
// grid 64 x 1024 thr: n = tid&127, f-chunk = tid>>7 (8 chunks of 128)
__global__ __launch_bounds__(1024) void k_sym_out(
    const float* __restrict__ sh, const float* __restrict__ W2s,
    const float* __restrict__ b2s, const int* __restrict__ sym_action,
    float* __restrict__ out)
{
  __shared__ float xs[1024];
  __shared__ float red[1024];
  __shared__ float lg[128];
  __shared__ float r2[16], r3[16];
  int b = blockIdx.x, tid = threadIdx.x;
  xs[tid] = sh[b*1024 + tid];
  __syncthreads();
  int n = tid & 127;
  int f0 = (tid >> 7) * 128;
  float acc = 0.f;
#pragma unroll 8
  for (int j = 0; j < 128; ++j){
    int f = f0 + j;
    acc = fmaf(xs[f], W2s[(size_t)f*ADIM + n], acc);
  }
  red[tid] = acc;
  __syncthreads();
  if (tid < 128){
    float s = b2s[tid];
#pragma unroll
    for (int j = 0; j < 8; ++j) s += red[tid + j*128];
    lg[tid] = s;
  }
  __syncthreads();
  float v = (tid < 128) ? lg[tid] : -1e30f;
  float mx = v;
  for (int off = 32; off; off >>= 1) mx = fmaxf(mx, __shfl_xor(mx, off));
  if ((tid & 63) == 0) r2[tid >> 6] = mx;
  __syncthreads();
  mx = -1e30f;
#pragma unroll
  for (int j = 0; j < 16; ++j) mx = fmaxf(mx, r2[j]);
  float e = (tid < 128) ? expf(v - mx) : 0.f;
  float se = e, ses = (tid < 128) ? e * v : 0.f;
  for (int off = 32; off; off >>= 1){ se += __shfl_xor(se, off); ses += __shfl_xor(ses, off); }
  __syncthreads();
  if ((tid & 63) == 0){ r2[tid >> 6] = se; r3[tid >> 6] = ses; }
  __syncthreads();
  if (tid == 0){
    float S = 0.f, SS = 0.f;
#pragma unroll
    for (int j = 0; j < 16; ++j){ S += r2[j]; SS += r3[j]; }
    float logZ = logf(S);
    out[64 + b]  = lg[sym_action[b]] - mx - logZ;  // logp_sym
    out[256 + b] = mx + logZ - SS / S;             // ent_sym
  }
}

// ---------------- value head: grid 64 x 1024 thr: n = tid&511, k-half = tid>>9 ----------------
__global__ __launch_bounds__(1024) void k_value_head(
    const float* __restrict__ cls, const float* __restrict__ Wc1,
    const float* __restrict__ bc1, const float* __restrict__ wc2,
    const float* __restrict__ bc2, float* __restrict__ out)
{
  __shared__ float xs[512];
  __shared__ float red[1024];
  __shared__ float r2[16];
  int b = blockIdx.x, tid = threadIdx.x;
  if (tid < 512) xs[tid] = cls[b*EDIM + tid];
  __syncthreads();
  int n = tid & 511;
  int k0 = (tid >> 9) * 256;
  float acc = 0.f;
#pragma unroll 8
  for (int j = 0; j < 256; ++j){
    int k = k0 + j;
    acc = fmaf(xs[k], Wc1[(size_t)k*EDIM + n], acc);
  }
  red[tid] = acc;
  __syncthreads();
  float p = 0.f;
  if (tid < 512){
    float h = red[tid] + red[tid + 512];
    p = fmaxf(h + bc1[tid], 0.f) * wc2[tid];
  }
  for (int off = 32; off; off >>= 1) p += __shfl_xor(p, off);
  if ((tid & 63) == 0) r2[tid >> 6] = p;
  __syncthreads();
  if (tid == 0){
    float s = bc2[0];
#pragma unroll
    for (int j = 0; j < 16; ++j) s += r2[j];
    out[128 + b] = s;  // val
  }
}

extern "C" void kernel_launch(void* const* d_in, const int* in_sizes, int n_in,
                              void* d_out, int out_size, void* d_ws, size_t ws_size,
                              hipStream_t stream){
  const float* states = (const float*)d_in[0];
  const float* cls    = (const float*)d_in[1];
  const float* W1p    = (const float*)d_in[2];
  const float* b1p    = (const float*)d_in[3];
  const float* w2p    = (const float*)d_in[4];
  const float* W1s    = (const float*)d_in[6];
  const float* b1s    = (const float*)d_in[7];
  const float* W2s    = (const float*)d_in[8];
  const float* b2s    = (const float*)d_in[9];
  const float* Wc1    = (const float*)d_in[10];
  const float* bc1    = (const float*)d_in[11];
  const float* wc2    = (const float*)d_in[12];
  const float* bc2    = (const float*)d_in[13];
  const int* lengths  = (const int*)d_in[14];
  const int* pos_a    = (const int*)d_in[15];
  const int* sym_a    = (const int*)d_in[16];
  float* out = (float*)d_out;

  char* ws = (char*)d_ws;
  u16* sbf      = (u16*)ws;                                  // 67108864 B (states bf16)
  u16* wt       = (u16*)(ws + 67108864);                     //  2097152 B (W1p^T bf16)
  float* scores = (float*)(ws + 67108864 + 2097152);         //   262144 B
  float* sh     = (float*)(ws + 67108864 + 2097152 + 262144);//   262144 B (sym hidden)

  k_cast_states<<<4096, 256, 0, stream>>>(states, sbf, 4194304);
  k_transpose_w1p<<<dim3(32, 32), dim3(32, 8), 0, stream>>>(W1p, wt);
  k_zero_scores<<<256, 256, 0, stream>>>(scores);
  k_gemm_scores<<<dim3(8, 512), 256, 0, stream>>>(sbf, wt, b1p, w2p, scores);
  k_pos_head<<<64, 256, 0, stream>>>(scores, lengths, pos_a, out);
  k_sym_h<<<dim3(4, 64), 1024, 0, stream>>>(states, W1s, b1s, pos_a, sh);
  k_sym_out<<<64, 1024, 0, stream>>>(sh, W2s, b2s, sym_a, out);
  k_value_head<<<64, 1024, 0, stream>>>(cls, Wc1, bc1, wc2, bc2, out);
}

// Round 3
// 395.709 us; speedup vs baseline: 1.3778x; 1.1079x over previous
//
#include <hip/hip_runtime.h>
#include <stdint.h>

#define BDIM 64
#define SDIM 1024
#define EDIM 512
#define ADIM 128
#define M_ROWS (BDIM*(SDIM-1))   // 65472
#define KDIM 1024                // 2E
#define NDIM 1024                // 2E

typedef unsigned short u16;
typedef __attribute__((ext_vector_type(8))) short short8;
typedef __attribute__((ext_vector_type(4))) float floatx4;
typedef const __attribute__((address_space(1))) void as1_void;
typedef __attribute__((address_space(3))) void as3_void;

__device__ inline u16 f2bf(float f){
  unsigned int u = __float_as_uint(f);
  u += 0x7fffu + ((u >> 16) & 1u);
  return (u16)(u >> 16);
}

// ---------------- cast states fp32 -> bf16, skipping dead rows (s >= lengths[b]) ----------------
// one chunk = 8 floats; 64 chunks per (b,s) row of 512 -> a 64-lane wave covers exactly
// one row, so the lengths[] branch is wave-uniform.
__global__ void k_cast_states(const float* __restrict__ src, u16* __restrict__ dst,
                              const int* __restrict__ lengths){
  int i = blockIdx.x*blockDim.x + threadIdx.x;
  int stride = gridDim.x*blockDim.x;
  for (; i < 4194304; i += stride){
    int row = i >> 6;              // (b*1024+s)
    int s = row & 1023, b = row >> 10;
    if (s >= lengths[b]) continue; // dead row: bf16 side never read
    const float4* sp = (const float4*)src + (size_t)i*2;
    float4 a = sp[0], c = sp[1];
    short8 v;
    v[0]=(short)f2bf(a.x); v[1]=(short)f2bf(a.y); v[2]=(short)f2bf(a.z); v[3]=(short)f2bf(a.w);
    v[4]=(short)f2bf(c.x); v[5]=(short)f2bf(c.y); v[6]=(short)f2bf(c.z); v[7]=(short)f2bf(c.w);
    ((short8*)dst)[i] = v;
  }
}

// ---------------- transpose+cast W1p (K x N) -> Wt (N x K) bf16, + zero scores ----------------
__global__ void k_transpose_w1p(const float* __restrict__ w, u16* __restrict__ wt,
                                float* __restrict__ scores){
  __shared__ float tile[32][33];
  int k0 = blockIdx.x*32, n0 = blockIdx.y*32;
  int tx = threadIdx.x, ty = threadIdx.y;
  // fused: zero the scores buffer (1024 blocks x 256 thr covers 262144 >= M_ROWS)
  int gid = (blockIdx.y*32 + blockIdx.x)*256 + ty*32 + tx;
  if (gid < M_ROWS) scores[gid] = 0.f;
  for (int j = ty; j < 32; j += 8) tile[j][tx] = w[(k0+j)*NDIM + n0 + tx];
  __syncthreads();
  for (int j = ty; j < 32; j += 8) wt[(n0+j)*KDIM + k0 + tx] = f2bf(tile[tx][j]);
}

// ---------------- main GEMM: scores[m] += sum_n relu(x_m.W1p + b1p)[n]*w2p[n] ----------------
// 1D grid 4096, decoded so the 8 nt-variants of one mt share an XCD (round-robin j%8):
//   nt = (j>>3)&7,  mt = (j>>6)*8 + (j&7)
// -> A row-block fetched once per XCD L2 instead of 8x from HBM.
// Dead-tile early-exit: tile fully inside one batch with s_min >= lengths[b]-1 is masked out.
__global__ __launch_bounds__(256, 2) void k_gemm_scores(
    const u16* __restrict__ sbf, const u16* __restrict__ wt,
    const float* __restrict__ b1p, const float* __restrict__ w2p,
    const int* __restrict__ lengths, float* __restrict__ scores)
{
  __shared__ short8 Ash[1024];   // 128 rows x 64 k (bf16) = 16 KB
  __shared__ short8 Bsh[1024];   // 128 n    x 64 k (bf16) = 16 KB
  const int tid = threadIdx.x;
  const int w = tid >> 6, l = tid & 63;
  const int j = blockIdx.x;
  const int nt = (j >> 3) & 7;
  const int mt = ((j >> 6) << 3) | (j & 7);

  // -------- dead-tile early exit (uniform) --------
  {
    int m_start = mt*128;
    int m_end = m_start + 127; if (m_end > M_ROWS-1) m_end = M_ROWS-1;
    int b0 = m_start / 1023, b1 = m_end / 1023;
    if (b0 == b1 && (m_start - b0*1023) >= lengths[b0]-1) return;
  }

  // -------- staging addresses (per-lane) --------
  const int lrow8 = l >> 3;            // 0..7 : row within 8-row group
  const int c = (l & 7) ^ lrow8;       // swizzled chunk this lane fetches
  const char* sbase = (const char*)sbf;
  const char* wbase = (const char*)wt;
  int offA[4], offB[4];
#pragma unroll
  for (int i = 0; i < 4; ++i){
    int mloc = (w*4 + i)*8 + lrow8;          // tile-local row 0..127
    int mg = mt*128 + mloc;
    if (mg >= M_ROWS) mg = 0;                // clamp; epilogue skips OOB rows
    int bb = mg / 1023;
    int ss = mg - bb*1023;
    offA[i] = bb*1048576 + ss*1024 + c*16;   // byte offset of (row, chunk c) at kt=0
    int nloc = (w*4 + i)*8 + lrow8;
    offB[i] = (nt*128 + nloc)*2048 + c*16;   // Wt row stride = 1024 bf16 = 2048 B
  }

  // -------- fragment read indices --------
  const int r = l & 15, q = l >> 4;
  const int wm = w & 1, wn = w >> 1;         // 2x2 wave grid, each 64x64
  int aIdx[4], bIdx[4];
#pragma unroll
  for (int i = 0; i < 4; ++i){
    int m = wm*64 + i*16 + r;
    aIdx[i] = m*8 + (q ^ (r & 7));
    int n = wn*64 + i*16 + r;
    bIdx[i] = n*8 + (q ^ (r & 7));
  }

  floatx4 acc[4][4];
#pragma unroll
  for (int a = 0; a < 4; ++a)
#pragma unroll
    for (int b = 0; b < 4; ++b) acc[a][b] = (floatx4)(0.0f);

  for (int step = 0; step < 16; ++step){
    const int ktb = step * 128;              // kt*2 bytes (kt = step*64 bf16)
    __syncthreads();                          // prev tile's reads complete
#pragma unroll
    for (int i = 0; i < 4; ++i){
      __builtin_amdgcn_global_load_lds((as1_void*)(sbase + offA[i] + ktb),
                                       (as3_void*)((char*)Ash + (w*4 + i)*1024), 16, 0, 0);
    }
#pragma unroll
    for (int i = 0; i < 4; ++i){
      __builtin_amdgcn_global_load_lds((as1_void*)(wbase + offB[i] + ktb),
                                       (as3_void*)((char*)Bsh + (w*4 + i)*1024), 16, 0, 0);
    }
    __syncthreads();                          // staging visible (vmcnt drain)
#pragma unroll
    for (int kh = 0; kh < 2; ++kh){
      short8 af[4], bf[4];
#pragma unroll
      for (int i = 0; i < 4; ++i) af[i] = Ash[aIdx[i] ^ (kh*4)];
#pragma unroll
      for (int i = 0; i < 4; ++i) bf[i] = Bsh[bIdx[i] ^ (kh*4)];
#pragma unroll
      for (int mi = 0; mi < 4; ++mi)
#pragma unroll
        for (int ni = 0; ni < 4; ++ni)
          acc[mi][ni] = __builtin_amdgcn_mfma_f32_16x16x32_bf16(af[mi], bf[ni], acc[mi][ni], 0, 0, 0);
    }
  }

  // -------- fused epilogue: relu(h + b1p)*w2p, reduce over n, atomic into scores --------
  const int mrow0 = mt*128 + wm*64;
  const int ncol0 = nt*128 + wn*64;
#pragma unroll
  for (int mi = 0; mi < 4; ++mi){
    float t0 = 0.f, t1 = 0.f, t2 = 0.f, t3 = 0.f;
#pragma unroll
    for (int ni = 0; ni < 4; ++ni){
      int n = ncol0 + ni*16 + r;
      float bb = b1p[n], ww = w2p[n];
      floatx4 a = acc[mi][ni];
      t0 += fmaxf(a[0] + bb, 0.f) * ww;
      t1 += fmaxf(a[1] + bb, 0.f) * ww;
      t2 += fmaxf(a[2] + bb, 0.f) * ww;
      t3 += fmaxf(a[3] + bb, 0.f) * ww;
    }
#pragma unroll
    for (int off = 1; off < 16; off <<= 1){
      t0 += __shfl_xor(t0, off);
      t1 += __shfl_xor(t1, off);
      t2 += __shfl_xor(t2, off);
      t3 += __shfl_xor(t3, off);
    }
    if (r == 0){
      int row = mrow0 + mi*16 + q*4;
      if (row + 0 < M_ROWS) atomicAdd(&scores[row + 0], t0);
      if (row + 1 < M_ROWS) atomicAdd(&scores[row + 1], t1);
      if (row + 2 < M_ROWS) atomicAdd(&scores[row + 2], t2);
      if (row + 3 < M_ROWS) atomicAdd(&scores[row + 3], t3);
    }
  }
}

// ---------------- masked log-softmax over positions: logp_pos, ent_pos ----------------
__global__ void k_pos_head(const float* __restrict__ scores, const int* __restrict__ lengths,
                           const int* __restrict__ pos_action, float* __restrict__ out){
  __shared__ float red[8];
  int b = blockIdx.x, tid = threadIdx.x;
  const float* sc = scores + b*(SDIM-1);
  int L = lengths[b] - 1;
  float mx = -1e30f;
  for (int s = tid; s < L; s += 256) mx = fmaxf(mx, sc[s]);
  for (int off = 32; off; off >>= 1) mx = fmaxf(mx, __shfl_xor(mx, off));
  if ((tid & 63) == 0) red[tid >> 6] = mx;
  __syncthreads();
  mx = fmaxf(fmaxf(red[0], red[1]), fmaxf(red[2], red[3]));
  float se = 0.f, ses = 0.f;
  for (int s = tid; s < L; s += 256){
    float v = sc[s];
    float e = expf(v - mx);
    se += e; ses += e * v;
  }
  for (int off = 32; off; off >>= 1){ se += __shfl_xor(se, off); ses += __shfl_xor(ses, off); }
  __syncthreads();
  if ((tid & 63) == 0){ red[tid >> 6] = se; red[4 + (tid >> 6)] = ses; }
  __syncthreads();
  if (tid == 0){
    float S = red[0] + red[1] + red[2] + red[3];
    float SS = red[4] + red[5] + red[6] + red[7];
    float logZ = logf(S);
    int pa = pos_action[b];
    out[b]       = sc[pa] - mx - logZ;      // logp_pos
    out[192 + b] = mx + logZ - SS / S;      // ent_pos
  }
}

// ---------------- symbol head stage 1: sh[b][n] = relu(x_b . W1s[:,n] + b1s[n]) ----------------
__global__ __launch_bounds__(1024) void k_sym_h(
    const float* __restrict__ states, const float* __restrict__ W1s,
    const float* __restrict__ b1s, const int* __restrict__ pos_action,
    float* __restrict__ sh)
{
  __shared__ float xs[1024];
  __shared__ float red[1024];
  int b = blockIdx.y, tid = threadIdx.x;
  int n0 = blockIdx.x * 256;
  int pa = pos_action[b];
  const float* src = states + (size_t)(b*SDIM + pa) * EDIM;  // e1||e2 contiguous
  xs[tid] = src[tid];
  __syncthreads();
  int n = n0 + (tid & 255);
  int k0 = (tid >> 8) * 256;
  float acc = 0.f;
#pragma unroll 8
  for (int jj = 0; jj < 256; ++jj){
    int k = k0 + jj;
    acc = fmaf(xs[k], W1s[(size_t)k*1024 + n], acc);
  }
  red[tid] = acc;
  __syncthreads();
  if (tid < 256){
    float s = red[tid] + red[tid+256] + red[tid+512] + red[tid+768];
    sh[b*1024 + n0 + tid] = fmaxf(s + b1s[n0 + tid], 0.f);
  }
}

// ---------------- symbol head stage 2: logits + log-softmax -> logp_sym, ent_sym ----------------
__global__ __launch_bounds__(1024) void k_sym_out(
    const float* __restrict__ sh, const float* __restrict__ W2s,
    const float* __restrict__ b2s, const int* __restrict__ sym_action,
    float* __restrict__ out)
{
  __shared__ float xs[1024];
  __shared__ float red[1024];
  __shared__ float lg[128];
  __shared__ float r2[16], r3[16];
  int b = blockIdx.x, tid = threadIdx.x;
  xs[tid] = sh[b*1024 + tid];
  __syncthreads();
  int n = tid & 127;
  int f0 = (tid >> 7) * 128;
  float acc = 0.f;
#pragma unroll 8
  for (int jj = 0; jj < 128; ++jj){
    int f = f0 + jj;
    acc = fmaf(xs[f], W2s[(size_t)f*ADIM + n], acc);
  }
  red[tid] = acc;
  __syncthreads();
  if (tid < 128){
    float s = b2s[tid];
#pragma unroll
    for (int jj = 0; jj < 8; ++jj) s += red[tid + jj*128];
    lg[tid] = s;
  }
  __syncthreads();
  float v = (tid < 128) ? lg[tid] : -1e30f;
  float mx = v;
  for (int off = 32; off; off >>= 1) mx = fmaxf(mx, __shfl_xor(mx, off));
  if ((tid & 63) == 0) r2[tid >> 6] = mx;
  __syncthreads();
  mx = -1e30f;
#pragma unroll
  for (int jj = 0; jj < 16; ++jj) mx = fmaxf(mx, r2[jj]);
  float e = (tid < 128) ? expf(v - mx) : 0.f;
  float se = e, ses = (tid < 128) ? e * v : 0.f;
  for (int off = 32; off; off >>= 1){ se += __shfl_xor(se, off); ses += __shfl_xor(ses, off); }
  __syncthreads();
  if ((tid & 63) == 0){ r2[tid >> 6] = se; r3[tid >> 6] = ses; }
  __syncthreads();
  if (tid == 0){
    float S = 0.f, SS = 0.f;
#pragma unroll
    for (int jj = 0; jj < 16; ++jj){ S += r2[jj]; SS += r3[jj]; }
    float logZ = logf(S);
    out[64 + b]  = lg[sym_action[b]] - mx - logZ;  // logp_sym
    out[256 + b] = mx + logZ - SS / S;             // ent_sym
  }
}

// ---------------- value head ----------------
__global__ __launch_bounds__(1024) void k_value_head(
    const float* __restrict__ cls, const float* __restrict__ Wc1,
    const float* __restrict__ bc1, const float* __restrict__ wc2,
    const float* __restrict__ bc2, float* __restrict__ out)
{
  __shared__ float xs[512];
  __shared__ float red[1024];
  __shared__ float r2[16];
  int b = blockIdx.x, tid = threadIdx.x;
  if (tid < 512) xs[tid] = cls[b*EDIM + tid];
  __syncthreads();
  int n = tid & 511;
  int k0 = (tid >> 9) * 256;
  float acc = 0.f;
#pragma unroll 8
  for (int jj = 0; jj < 256; ++jj){
    int k = k0 + jj;
    acc = fmaf(xs[k], Wc1[(size_t)k*EDIM + n], acc);
  }
  red[tid] = acc;
  __syncthreads();
  float p = 0.f;
  if (tid < 512){
    float h = red[tid] + red[tid + 512];
    p = fmaxf(h + bc1[tid], 0.f) * wc2[tid];
  }
  for (int off = 32; off; off >>= 1) p += __shfl_xor(p, off);
  if ((tid & 63) == 0) r2[tid >> 6] = p;
  __syncthreads();
  if (tid == 0){
    float s = bc2[0];
#pragma unroll
    for (int jj = 0; jj < 16; ++jj) s += r2[jj];
    out[128 + b] = s;  // val
  }
}

extern "C" void kernel_launch(void* const* d_in, const int* in_sizes, int n_in,
                              void* d_out, int out_size, void* d_ws, size_t ws_size,
                              hipStream_t stream){
  const float* states = (const float*)d_in[0];
  const float* cls    = (const float*)d_in[1];
  const float* W1p    = (const float*)d_in[2];
  const float* b1p    = (const float*)d_in[3];
  const float* w2p    = (const float*)d_in[4];
  const float* W1s    = (const float*)d_in[6];
  const float* b1s    = (const float*)d_in[7];
  const float* W2s    = (const float*)d_in[8];
  const float* b2s    = (const float*)d_in[9];
  const float* Wc1    = (const float*)d_in[10];
  const float* bc1    = (const float*)d_in[11];
  const float* wc2    = (const float*)d_in[12];
  const float* bc2    = (const float*)d_in[13];
  const int* lengths  = (const int*)d_in[14];
  const int* pos_a    = (const int*)d_in[15];
  const int* sym_a    = (const int*)d_in[16];
  float* out = (float*)d_out;

  char* ws = (char*)d_ws;
  u16* sbf      = (u16*)ws;                                  // 67108864 B (states bf16)
  u16* wt       = (u16*)(ws + 67108864);                     //  2097152 B (W1p^T bf16)
  float* scores = (float*)(ws + 67108864 + 2097152);         //   262144 B
  float* sh     = (float*)(ws + 67108864 + 2097152 + 262144);//   262144 B (sym hidden)

  k_cast_states<<<4096, 256, 0, stream>>>(states, sbf, lengths);
  k_transpose_w1p<<<dim3(32, 32), dim3(32, 8), 0, stream>>>(W1p, wt, scores);
  k_gemm_scores<<<4096, 256, 0, stream>>>(sbf, wt, b1p, w2p, lengths, scores);
  k_pos_head<<<64, 256, 0, stream>>>(scores, lengths, pos_a, out);
  k_sym_h<<<dim3(4, 64), 1024, 0, stream>>>(states, W1s, b1s, pos_a, sh);
  k_sym_out<<<64, 1024, 0, stream>>>(sh, W2s, b2s, sym_a, out);
  k_value_head<<<64, 1024, 0, stream>>>(cls, Wc1, bc1, wc2, bc2, out);
}

// Round 4
// 336.956 us; speedup vs baseline: 1.6180x; 1.1744x over previous
//
#include <hip/hip_runtime.h>
#include <stdint.h>

#define BDIM 64
#define SDIM 1024
#define EDIM 512
#define ADIM 128
#define M_ROWS (BDIM*(SDIM-1))   // 65472
#define KDIM 1024                // 2E
#define NDIM 1024                // 2E

typedef unsigned short u16;
typedef __attribute__((ext_vector_type(8))) short short8;
typedef __attribute__((ext_vector_type(4))) float floatx4;
typedef const __attribute__((address_space(1))) void as1_void;
typedef __attribute__((address_space(3))) void as3_void;

__device__ inline u16 f2bf(float f){
  unsigned int u = __float_as_uint(f);
  u += 0x7fffu + ((u >> 16) & 1u);
  return (u16)(u >> 16);
}

// ================= prep kernel: role-split by blockIdx =================
// [0,1024): cast states->bf16 (live rows)   [1024,1280): W1p transpose
// 1280: live-tile compaction                [1281,1537): sym stage1
// [1537,1601): value head
__global__ __launch_bounds__(1024) void k_prep(
    const float* __restrict__ states, const float* __restrict__ cls,
    const float* __restrict__ W1p, const float* __restrict__ W1s,
    const float* __restrict__ b1s, const float* __restrict__ Wc1,
    const float* __restrict__ bc1, const float* __restrict__ wc2,
    const float* __restrict__ bc2, const int* __restrict__ lengths,
    const int* __restrict__ pos_action,
    u16* __restrict__ sbf, u16* __restrict__ wt,
    float* __restrict__ sh, int* __restrict__ live_list,
    float* __restrict__ out)
{
  __shared__ float smem[64*65];
  const int blk = blockIdx.x, tid = threadIdx.x;

  if (blk < 1024){
    int i = blk*1024 + tid;
#pragma unroll
    for (int it = 0; it < 4; ++it, i += 1048576){
      int row = i >> 6;
      int s = row & 1023, b = row >> 10;
      if (s < lengths[b]){
        const float4* sp = (const float4*)states + (size_t)i*2;
        float4 a = sp[0], c = sp[1];
        short8 v;
        v[0]=(short)f2bf(a.x); v[1]=(short)f2bf(a.y); v[2]=(short)f2bf(a.z); v[3]=(short)f2bf(a.w);
        v[4]=(short)f2bf(c.x); v[5]=(short)f2bf(c.y); v[6]=(short)f2bf(c.z); v[7]=(short)f2bf(c.w);
        ((short8*)sbf)[i] = v;
      }
    }
    return;
  }
  if (blk < 1280){
    float (*tile)[65] = (float(*)[65])smem;
    int tb = blk - 1024;
    int k0 = (tb & 15)*64, n0 = (tb >> 4)*64;
    int tx = tid & 63, ty = tid >> 6;
    for (int j = ty; j < 64; j += 16) tile[j][tx] = W1p[(size_t)(k0+j)*NDIM + n0 + tx];
    __syncthreads();
    for (int j = ty; j < 64; j += 16) wt[(size_t)(n0+j)*KDIM + k0 + tx] = f2bf(tile[tx][j]);
    return;
  }
  if (blk == 1280){
    int* flags = (int*)smem;
    if (tid < 512){
      int m_start = tid*128;
      int m_end = m_start + 127; if (m_end > M_ROWS-1) m_end = M_ROWS-1;
      int b0 = m_start / 1023, b1 = m_end / 1023;
      flags[tid] = !(b0 == b1 && (m_start - b0*1023) >= lengths[b0]-1);
    }
    __syncthreads();
    if (tid == 0){
      int c = 0;
      for (int i2 = 0; i2 < 512; ++i2) if (flags[i2]) live_list[c++] = i2;
      live_list[512] = c;
    }
    return;
  }
  if (blk < 1537){
    float* xs  = smem;
    float* red = smem + 1024;
    int rb = blk - 1281;
    int b = rb >> 2, n0 = (rb & 3)*256;
    int pa = pos_action[b];
    const float* src = states + (size_t)(b*SDIM + pa) * EDIM;
    xs[tid] = src[tid];
    __syncthreads();
    int n = n0 + (tid & 255);
    int k0 = (tid >> 8) * 256;
    float acc = 0.f;
#pragma unroll 8
    for (int jj = 0; jj < 256; ++jj){
      int k = k0 + jj;
      acc = fmaf(xs[k], W1s[(size_t)k*1024 + n], acc);
    }
    red[tid] = acc;
    __syncthreads();
    if (tid < 256){
      float s = red[tid] + red[tid+256] + red[tid+512] + red[tid+768];
      sh[b*1024 + n0 + tid] = fmaxf(s + b1s[n0 + tid], 0.f);
    }
    return;
  }
  {
    float* xs  = smem;
    float* red = smem + 512;
    float* r2  = smem + 1536;
    int b = blk - 1537;
    if (tid < 512) xs[tid] = cls[b*EDIM + tid];
    __syncthreads();
    int n = tid & 511;
    int k0 = (tid >> 9) * 256;
    float acc = 0.f;
#pragma unroll 8
    for (int jj = 0; jj < 256; ++jj){
      int k = k0 + jj;
      acc = fmaf(xs[k], Wc1[(size_t)k*EDIM + n], acc);
    }
    red[tid] = acc;
    __syncthreads();
    float p = 0.f;
    if (tid < 512){
      float h = red[tid] + red[tid + 512];
      p = fmaxf(h + bc1[tid], 0.f) * wc2[tid];
    }
    for (int off = 32; off; off >>= 1) p += __shfl_xor(p, off);
    if ((tid & 63) == 0) r2[tid >> 6] = p;
    __syncthreads();
    if (tid == 0){
      float s = bc2[0];
#pragma unroll
      for (int jj = 0; jj < 16; ++jj) s += r2[jj];
      out[128 + b] = s;
    }
  }
}

// ================= main GEMM =================
// scores_p[nt][m] = sum_{n in nt's 128-chunk} relu(x_m.W1p + b1p)[n]*w2p[n]
__global__ __launch_bounds__(256, 2) void k_gemm_scores(
    const u16* __restrict__ sbf, const u16* __restrict__ wt,
    const float* __restrict__ b1p, const float* __restrict__ w2p,
    const int* __restrict__ live_list, float* __restrict__ scores_p)
{
  __shared__ short8 Ash[1024];
  __shared__ short8 Bsh[1024];
  __shared__ float comb[2][128];   // wn=0 partials, per wm half
  const int tid = threadIdx.x;
  const int w = tid >> 6, l = tid & 63;
  const int j = blockIdx.x;
  const int tl = ((j >> 6) << 3) | (j & 7);
  const int nt = (j >> 3) & 7;
  if (tl >= live_list[512]) return;
  const int mt = live_list[tl];

  const int lrow8 = l >> 3;
  const int c = (l & 7) ^ lrow8;
  const char* sbase = (const char*)sbf;
  const char* wbase = (const char*)wt;
  int offA[4], offB[4];
#pragma unroll
  for (int i = 0; i < 4; ++i){
    int mloc = (w*4 + i)*8 + lrow8;
    int mg = mt*128 + mloc;
    if (mg >= M_ROWS) mg = 0;
    int bb = mg / 1023;
    int ss = mg - bb*1023;
    offA[i] = bb*1048576 + ss*1024 + c*16;
    int nloc = (w*4 + i)*8 + lrow8;
    offB[i] = (nt*128 + nloc)*2048 + c*16;
  }

  const int r = l & 15, q = l >> 4;
  const int wm = w & 1, wn = w >> 1;
  int aIdx[4], bIdx[4];
#pragma unroll
  for (int i = 0; i < 4; ++i){
    int m = wm*64 + i*16 + r;
    aIdx[i] = m*8 + (q ^ (r & 7));
    int n = wn*64 + i*16 + r;
    bIdx[i] = n*8 + (q ^ (r & 7));
  }

  floatx4 acc[4][4];
#pragma unroll
  for (int a = 0; a < 4; ++a)
#pragma unroll
    for (int b = 0; b < 4; ++b) acc[a][b] = (floatx4)(0.0f);

  for (int step = 0; step < 16; ++step){
    const int ktb = step * 128;
    __syncthreads();
#pragma unroll
    for (int i = 0; i < 4; ++i){
      __builtin_amdgcn_global_load_lds((as1_void*)(sbase + offA[i] + ktb),
                                       (as3_void*)((char*)Ash + (w*4 + i)*1024), 16, 0, 0);
    }
#pragma unroll
    for (int i = 0; i < 4; ++i){
      __builtin_amdgcn_global_load_lds((as1_void*)(wbase + offB[i] + ktb),
                                       (as3_void*)((char*)Bsh + (w*4 + i)*1024), 16, 0, 0);
    }
    __syncthreads();
#pragma unroll
    for (int kh = 0; kh < 2; ++kh){
      short8 af[4], bf[4];
#pragma unroll
      for (int i = 0; i < 4; ++i) af[i] = Ash[aIdx[i] ^ (kh*4)];
#pragma unroll
      for (int i = 0; i < 4; ++i) bf[i] = Bsh[bIdx[i] ^ (kh*4)];
#pragma unroll
      for (int mi = 0; mi < 4; ++mi)
#pragma unroll
        for (int ni = 0; ni < 4; ++ni)
          acc[mi][ni] = __builtin_amdgcn_mfma_f32_16x16x32_bf16(af[mi], bf[ni], acc[mi][ni], 0, 0, 0);
    }
  }

  // -------- epilogue: per-wave reduce over its 64-col half, combine halves in LDS,
  // wn=1 stores the 128-col partial. All barriers wave-uniform. --------
  const int mrow0 = mt*128 + wm*64;
  const int ncol0 = nt*128 + wn*64;
  float* dst = scores_p + (nt << 16);
#pragma unroll
  for (int mi = 0; mi < 4; ++mi){
    float t0 = 0.f, t1 = 0.f, t2 = 0.f, t3 = 0.f;
#pragma unroll
    for (int ni = 0; ni < 4; ++ni){
      int n = ncol0 + ni*16 + r;
      float bb = b1p[n], ww = w2p[n];
      floatx4 a = acc[mi][ni];
      t0 += fmaxf(a[0] + bb, 0.f) * ww;
      t1 += fmaxf(a[1] + bb, 0.f) * ww;
      t2 += fmaxf(a[2] + bb, 0.f) * ww;
      t3 += fmaxf(a[3] + bb, 0.f) * ww;
    }
#pragma unroll
    for (int off = 1; off < 16; off <<= 1){
      t0 += __shfl_xor(t0, off);
      t1 += __shfl_xor(t1, off);
      t2 += __shfl_xor(t2, off);
      t3 += __shfl_xor(t3, off);
    }
    // lane r==0 of each quad holds 4 row-sums for rows (mi*16 + q*4 .. +3)
    int lrow = mi*16 + q*4;
    if (wn == 0 && r == 0){
      comb[wm][lrow+0] = t0; comb[wm][lrow+1] = t1;
      comb[wm][lrow+2] = t2; comb[wm][lrow+3] = t3;
    }
    __syncthreads();
    if (wn == 1 && r == 0){
      int row = mrow0 + lrow;
      float4 v4 = make_float4(t0 + comb[wm][lrow+0], t1 + comb[wm][lrow+1],
                              t2 + comb[wm][lrow+2], t3 + comb[wm][lrow+3]);
      if (row + 3 < M_ROWS) *(float4*)(dst + row) = v4;
      else {
        if (row   < M_ROWS) dst[row]   = v4.x;
        if (row+1 < M_ROWS) dst[row+1] = v4.y;
        if (row+2 < M_ROWS) dst[row+2] = v4.z;
      }
    }
    __syncthreads();
  }
}

// ================= post: pos softmax (blocks 0-63) + sym_out (64-127) =================
__global__ __launch_bounds__(1024) void k_post(
    const float* __restrict__ scores_p, const float* __restrict__ sh,
    const float* __restrict__ W2s, const float* __restrict__ b2s,
    const int* __restrict__ lengths, const int* __restrict__ pos_action,
    const int* __restrict__ sym_action, float* __restrict__ out)
{
  __shared__ float smem[2208];
  const int blk = blockIdx.x, tid = threadIdx.x;
  if (blk < 64){
    float* sc   = smem;
    float* red  = smem + 1024;
    float* red2 = smem + 1040;
    int b = blk;
    int L = lengths[b] - 1;
    const float* sp = scores_p + b*1023;
    float mx = -1e30f;
    for (int s = tid; s < L; s += 1024){
      float v = 0.f;
#pragma unroll
      for (int ntI = 0; ntI < 8; ++ntI) v += sp[(ntI << 16) + s];
      sc[s] = v;
      mx = fmaxf(mx, v);
    }
    for (int off = 32; off; off >>= 1) mx = fmaxf(mx, __shfl_xor(mx, off));
    if ((tid & 63) == 0) red[tid >> 6] = mx;
    __syncthreads();
    mx = -1e30f;
#pragma unroll
    for (int jj = 0; jj < 16; ++jj) mx = fmaxf(mx, red[jj]);
    float se = 0.f, ses = 0.f;
    for (int s = tid; s < L; s += 1024){
      float v = sc[s];
      float e = expf(v - mx);
      se += e; ses += e * v;
    }
    for (int off = 32; off; off >>= 1){ se += __shfl_xor(se, off); ses += __shfl_xor(ses, off); }
    __syncthreads();
    if ((tid & 63) == 0){ red[tid >> 6] = se; red2[tid >> 6] = ses; }
    __syncthreads();
    if (tid == 0){
      float S = 0.f, SS = 0.f;
#pragma unroll
      for (int jj = 0; jj < 16; ++jj){ S += red[jj]; SS += red2[jj]; }
      float logZ = logf(S);
      int pa = pos_action[b];
      out[b]       = sc[pa] - mx - logZ;
      out[192 + b] = mx + logZ - SS / S;
    }
    return;
  }
  {
    float* xs  = smem;
    float* red = smem + 1024;
    float* lg  = smem + 2048;
    float* r2  = smem + 2176;
    float* r3  = smem + 2192;
    int b = blk - 64;
    xs[tid] = sh[b*1024 + tid];
    __syncthreads();
    int n = tid & 127;
    int f0 = (tid >> 7) * 128;
    float acc = 0.f;
#pragma unroll 8
    for (int jj = 0; jj < 128; ++jj){
      int f = f0 + jj;
      acc = fmaf(xs[f], W2s[(size_t)f*ADIM + n], acc);
    }
    red[tid] = acc;
    __syncthreads();
    if (tid < 128){
      float s = b2s[tid];
#pragma unroll
      for (int jj = 0; jj < 8; ++jj) s += red[tid + jj*128];
      lg[tid] = s;
    }
    __syncthreads();
    float v = (tid < 128) ? lg[tid] : -1e30f;
    float mx = v;
    for (int off = 32; off; off >>= 1) mx = fmaxf(mx, __shfl_xor(mx, off));
    if ((tid & 63) == 0) r2[tid >> 6] = mx;
    __syncthreads();
    mx = -1e30f;
#pragma unroll
    for (int jj = 0; jj < 16; ++jj) mx = fmaxf(mx, r2[jj]);
    float e = (tid < 128) ? expf(v - mx) : 0.f;
    float se = e, ses = (tid < 128) ? e * v : 0.f;
    for (int off = 32; off; off >>= 1){ se += __shfl_xor(se, off); ses += __shfl_xor(ses, off); }
    __syncthreads();
    if ((tid & 63) == 0){ r2[tid >> 6] = se; r3[tid >> 6] = ses; }
    __syncthreads();
    if (tid == 0){
      float S = 0.f, SS = 0.f;
#pragma unroll
      for (int jj = 0; jj < 16; ++jj){ S += r2[jj]; SS += r3[jj]; }
      float logZ = logf(S);
      out[64 + b]  = lg[sym_action[b]] - mx - logZ;
      out[256 + b] = mx + logZ - SS / S;
    }
  }
}

extern "C" void kernel_launch(void* const* d_in, const int* in_sizes, int n_in,
                              void* d_out, int out_size, void* d_ws, size_t ws_size,
                              hipStream_t stream){
  const float* states = (const float*)d_in[0];
  const float* cls    = (const float*)d_in[1];
  const float* W1p    = (const float*)d_in[2];
  const float* b1p    = (const float*)d_in[3];
  const float* w2p    = (const float*)d_in[4];
  const float* W1s    = (const float*)d_in[6];
  const float* b1s    = (const float*)d_in[7];
  const float* W2s    = (const float*)d_in[8];
  const float* b2s    = (const float*)d_in[9];
  const float* Wc1    = (const float*)d_in[10];
  const float* bc1    = (const float*)d_in[11];
  const float* wc2    = (const float*)d_in[12];
  const float* bc2    = (const float*)d_in[13];
  const int* lengths  = (const int*)d_in[14];
  const int* pos_a    = (const int*)d_in[15];
  const int* sym_a    = (const int*)d_in[16];
  float* out = (float*)d_out;

  char* ws = (char*)d_ws;
  u16* sbf        = (u16*)ws;                          // 67108864 B
  u16* wt         = (u16*)(ws + 67108864);             //  2097152 B
  float* scores_p = (float*)(ws + 69206016);           //  2097152 B (8 x 65536)
  float* sh       = (float*)(ws + 71303168);           //   262144 B
  int* live       = (int*)(ws + 71565312);             //     4096 B

  k_prep<<<1601, 1024, 0, stream>>>(states, cls, W1p, W1s, b1s, Wc1, bc1, wc2, bc2,
                                    lengths, pos_a, sbf, wt, sh, live, out);
  k_gemm_scores<<<4096, 256, 0, stream>>>(sbf, wt, b1p, w2p, live, scores_p);
  k_post<<<128, 1024, 0, stream>>>(scores_p, sh, W2s, b2s, lengths, pos_a, sym_a, out);
}

// Round 5
// 321.222 us; speedup vs baseline: 1.6973x; 1.0490x over previous
//
#include <hip/hip_runtime.h>
#include <stdint.h>

#define BDIM 64
#define SDIM 1024
#define EDIM 512
#define ADIM 128
#define M_ROWS (BDIM*(SDIM-1))   // 65472
#define KDIM 1024                // 2E
#define NDIM 1024                // 2E

typedef unsigned short u16;
typedef __attribute__((ext_vector_type(8))) short short8;
typedef __attribute__((ext_vector_type(4))) float floatx4;
typedef const __attribute__((address_space(1))) void as1_void;
typedef __attribute__((address_space(3))) void as3_void;

__device__ inline u16 f2bf(float f){
  unsigned int u = __float_as_uint(f);
  u += 0x7fffu + ((u >> 16) & 1u);
  return (u16)(u >> 16);
}

// ================= prep kernel: role-split by blockIdx =================
// [0,1024): cast states->bf16 (live rows)   [1024,1280): W1p transpose + zero scores
// 1280: row compaction (cum + rows map)     [1281,1537): sym stage1
// [1537,1601): value head
__global__ __launch_bounds__(1024) void k_prep(
    const float* __restrict__ states, const float* __restrict__ cls,
    const float* __restrict__ W1p, const float* __restrict__ W1s,
    const float* __restrict__ b1s, const float* __restrict__ Wc1,
    const float* __restrict__ bc1, const float* __restrict__ wc2,
    const float* __restrict__ bc2, const int* __restrict__ lengths,
    const int* __restrict__ pos_action,
    u16* __restrict__ sbf, u16* __restrict__ wt,
    float* __restrict__ sh, int* __restrict__ rows, int* __restrict__ aux,
    float* __restrict__ scores, float* __restrict__ out)
{
  __shared__ float smem[64*65];
  const int blk = blockIdx.x, tid = threadIdx.x;

  if (blk < 1024){
    int i = blk*1024 + tid;
#pragma unroll
    for (int it = 0; it < 4; ++it, i += 1048576){
      int row = i >> 6;
      int s = row & 1023, b = row >> 10;
      if (s < lengths[b]){
        const float4* sp = (const float4*)states + (size_t)i*2;
        float4 a = sp[0], c = sp[1];
        short8 v;
        v[0]=(short)f2bf(a.x); v[1]=(short)f2bf(a.y); v[2]=(short)f2bf(a.z); v[3]=(short)f2bf(a.w);
        v[4]=(short)f2bf(c.x); v[5]=(short)f2bf(c.y); v[6]=(short)f2bf(c.z); v[7]=(short)f2bf(c.w);
        ((short8*)sbf)[i] = v;
      }
    }
    return;
  }
  if (blk < 1280){
    float (*tile)[65] = (float(*)[65])smem;
    int tb = blk - 1024;
    // fused: zero compact scores (65536 floats; only tb<64 blocks write)
    int zi = tb*1024 + tid;
    if (zi < 65536) scores[zi] = 0.f;
    int k0 = (tb & 15)*64, n0 = (tb >> 4)*64;
    int tx = tid & 63, ty = tid >> 6;
    for (int j = ty; j < 64; j += 16) tile[j][tx] = W1p[(size_t)(k0+j)*NDIM + n0 + tx];
    __syncthreads();
    for (int j = ty; j < 64; j += 16) wt[(size_t)(n0+j)*KDIM + k0 + tx] = f2bf(tile[tx][j]);
    return;
  }
  if (blk == 1280){
    // ---- row compaction: cum[b] = sum_{b'<b}(len-1); rows[cum[b]+s] = b*1024+s ----
    __shared__ int scum[65];
    if (tid == 0){
      int c = 0;
      for (int b = 0; b < 64; ++b){ scum[b] = c; c += lengths[b] - 1; }
      scum[64] = c;
    }
    __syncthreads();
    if (tid < 65) aux[tid] = scum[tid];
    if (tid == 0){
      aux[70] = scum[64];                 // total live rows
      aux[71] = (scum[64] + 127) >> 7;    // ntiles
    }
    for (int b = 0; b < 64; ++b){
      int base = scum[b], L = scum[b+1] - scum[b];
      for (int i2 = tid; i2 < L; i2 += 1024) rows[base + i2] = (b << 10) + i2;
    }
    return;
  }
  if (blk < 1537){
    float* xs  = smem;
    float* red = smem + 1024;
    int rb = blk - 1281;
    int b = rb >> 2, n0 = (rb & 3)*256;
    int pa = pos_action[b];
    const float* src = states + (size_t)(b*SDIM + pa) * EDIM;
    xs[tid] = src[tid];
    __syncthreads();
    int n = n0 + (tid & 255);
    int k0 = (tid >> 8) * 256;
    float acc = 0.f;
#pragma unroll 8
    for (int jj = 0; jj < 256; ++jj){
      int k = k0 + jj;
      acc = fmaf(xs[k], W1s[(size_t)k*1024 + n], acc);
    }
    red[tid] = acc;
    __syncthreads();
    if (tid < 256){
      float s = red[tid] + red[tid+256] + red[tid+512] + red[tid+768];
      sh[b*1024 + n0 + tid] = fmaxf(s + b1s[n0 + tid], 0.f);
    }
    return;
  }
  {
    float* xs  = smem;
    float* red = smem + 512;
    float* r2  = smem + 1536;
    int b = blk - 1537;
    if (tid < 512) xs[tid] = cls[b*EDIM + tid];
    __syncthreads();
    int n = tid & 511;
    int k0 = (tid >> 9) * 256;
    float acc = 0.f;
#pragma unroll 8
    for (int jj = 0; jj < 256; ++jj){
      int k = k0 + jj;
      acc = fmaf(xs[k], Wc1[(size_t)k*EDIM + n], acc);
    }
    red[tid] = acc;
    __syncthreads();
    float p = 0.f;
    if (tid < 512){
      float h = red[tid] + red[tid + 512];
      p = fmaxf(h + bc1[tid], 0.f) * wc2[tid];
    }
    for (int off = 32; off; off >>= 1) p += __shfl_xor(p, off);
    if ((tid & 63) == 0) r2[tid >> 6] = p;
    __syncthreads();
    if (tid == 0){
      float s = bc2[0];
#pragma unroll
      for (int jj = 0; jj < 16; ++jj) s += r2[jj];
      out[128 + b] = s;
    }
  }
}

// ================= main GEMM over COMPACTED live rows =================
// scores[mc] += sum_{n in nt's 128-chunk} relu(x_{rows[mc]}.W1p + b1p)[n]*w2p[n]
// block j: tl = ((j>>6)<<3)|(j&7)  (XCD phase = tl&7, so all 8 nt-variants of a
// tile share an XCD L2); nt = (j>>3)&7; exit if tl >= ntiles.
__global__ __launch_bounds__(256, 2) void k_gemm_scores(
    const u16* __restrict__ sbf, const u16* __restrict__ wt,
    const float* __restrict__ b1p, const float* __restrict__ w2p,
    const int* __restrict__ rows, const int* __restrict__ aux,
    float* __restrict__ scores)
{
  __shared__ short8 Ash[1024];
  __shared__ short8 Bsh[1024];
  const int tid = threadIdx.x;
  const int w = tid >> 6, l = tid & 63;
  const int j = blockIdx.x;
  const int tl = ((j >> 6) << 3) | (j & 7);
  const int nt = (j >> 3) & 7;
  const int total = aux[70];
  if (tl >= aux[71]) return;

  const int lrow8 = l >> 3;
  const int c = (l & 7) ^ lrow8;
  const char* sbase = (const char*)sbf;
  const char* wbase = (const char*)wt;
  int offA[4], offB[4];
#pragma unroll
  for (int i = 0; i < 4; ++i){
    int mloc = (w*4 + i)*8 + lrow8;
    int mg = tl*128 + mloc;
    if (mg >= total) mg = 0;                 // pad rows: read row 0, store-guarded
    int rs = rows[mg];                       // b*1024 + s
    offA[i] = rs*1024 + c*16;                // A row stride = 512 bf16 = 1024 B
    int nloc = (w*4 + i)*8 + lrow8;
    offB[i] = (nt*128 + nloc)*2048 + c*16;   // Wt row stride = 1024 bf16 = 2048 B
  }

  const int r = l & 15, q = l >> 4;
  const int wm = w & 1, wn = w >> 1;
  int aIdx[4], bIdx[4];
#pragma unroll
  for (int i = 0; i < 4; ++i){
    int m = wm*64 + i*16 + r;
    aIdx[i] = m*8 + (q ^ (r & 7));
    int n = wn*64 + i*16 + r;
    bIdx[i] = n*8 + (q ^ (r & 7));
  }

  floatx4 acc[4][4];
#pragma unroll
  for (int a = 0; a < 4; ++a)
#pragma unroll
    for (int b = 0; b < 4; ++b) acc[a][b] = (floatx4)(0.0f);

  for (int step = 0; step < 16; ++step){
    const int ktb = step * 128;
    __syncthreads();
#pragma unroll
    for (int i = 0; i < 4; ++i){
      __builtin_amdgcn_global_load_lds((as1_void*)(sbase + offA[i] + ktb),
                                       (as3_void*)((char*)Ash + (w*4 + i)*1024), 16, 0, 0);
    }
#pragma unroll
    for (int i = 0; i < 4; ++i){
      __builtin_amdgcn_global_load_lds((as1_void*)(wbase + offB[i] + ktb),
                                       (as3_void*)((char*)Bsh + (w*4 + i)*1024), 16, 0, 0);
    }
    __syncthreads();
#pragma unroll
    for (int kh = 0; kh < 2; ++kh){
      short8 af[4], bf[4];
#pragma unroll
      for (int i = 0; i < 4; ++i) af[i] = Ash[aIdx[i] ^ (kh*4)];
#pragma unroll
      for (int i = 0; i < 4; ++i) bf[i] = Bsh[bIdx[i] ^ (kh*4)];
#pragma unroll
      for (int mi = 0; mi < 4; ++mi)
#pragma unroll
        for (int ni = 0; ni < 4; ++ni)
          acc[mi][ni] = __builtin_amdgcn_mfma_f32_16x16x32_bf16(af[mi], bf[ni], acc[mi][ni], 0, 0, 0);
    }
  }

  // -------- epilogue: relu(h+b1p)*w2p, quad-reduce over n, atomicAdd compact scores --------
  const int mrow0 = tl*128 + wm*64;
  const int ncol0 = nt*128 + wn*64;
#pragma unroll
  for (int mi = 0; mi < 4; ++mi){
    float t0 = 0.f, t1 = 0.f, t2 = 0.f, t3 = 0.f;
#pragma unroll
    for (int ni = 0; ni < 4; ++ni){
      int n = ncol0 + ni*16 + r;
      float bb = b1p[n], ww = w2p[n];
      floatx4 a = acc[mi][ni];
      t0 += fmaxf(a[0] + bb, 0.f) * ww;
      t1 += fmaxf(a[1] + bb, 0.f) * ww;
      t2 += fmaxf(a[2] + bb, 0.f) * ww;
      t3 += fmaxf(a[3] + bb, 0.f) * ww;
    }
#pragma unroll
    for (int off = 1; off < 16; off <<= 1){
      t0 += __shfl_xor(t0, off);
      t1 += __shfl_xor(t1, off);
      t2 += __shfl_xor(t2, off);
      t3 += __shfl_xor(t3, off);
    }
    if (r == 0){
      int row = mrow0 + mi*16 + q*4;
      if (row + 0 < total) atomicAdd(&scores[row + 0], t0);
      if (row + 1 < total) atomicAdd(&scores[row + 1], t1);
      if (row + 2 < total) atomicAdd(&scores[row + 2], t2);
      if (row + 3 < total) atomicAdd(&scores[row + 3], t3);
    }
  }
}

// ================= post: pos softmax (blocks 0-63) + sym_out (64-127) =================
__global__ __launch_bounds__(1024) void k_post(
    const float* __restrict__ scores, const float* __restrict__ sh,
    const float* __restrict__ W2s, const float* __restrict__ b2s,
    const int* __restrict__ aux, const int* __restrict__ lengths,
    const int* __restrict__ pos_action, const int* __restrict__ sym_action,
    float* __restrict__ out)
{
  __shared__ float smem[2208];
  const int blk = blockIdx.x, tid = threadIdx.x;
  if (blk < 64){
    float* sc   = smem;
    float* red  = smem + 1024;
    float* red2 = smem + 1040;
    int b = blk;
    int L = lengths[b] - 1;
    const float* sp = scores + aux[b];   // compact base for batch b
    float mx = -1e30f;
    for (int s = tid; s < L; s += 1024){
      float v = sp[s];
      sc[s] = v;
      mx = fmaxf(mx, v);
    }
    for (int off = 32; off; off >>= 1) mx = fmaxf(mx, __shfl_xor(mx, off));
    if ((tid & 63) == 0) red[tid >> 6] = mx;
    __syncthreads();
    mx = -1e30f;
#pragma unroll
    for (int jj = 0; jj < 16; ++jj) mx = fmaxf(mx, red[jj]);
    float se = 0.f, ses = 0.f;
    for (int s = tid; s < L; s += 1024){
      float v = sc[s];
      float e = expf(v - mx);
      se += e; ses += e * v;
    }
    for (int off = 32; off; off >>= 1){ se += __shfl_xor(se, off); ses += __shfl_xor(ses, off); }
    __syncthreads();
    if ((tid & 63) == 0){ red[tid >> 6] = se; red2[tid >> 6] = ses; }
    __syncthreads();
    if (tid == 0){
      float S = 0.f, SS = 0.f;
#pragma unroll
      for (int jj = 0; jj < 16; ++jj){ S += red[jj]; SS += red2[jj]; }
      float logZ = logf(S);
      int pa = pos_action[b];
      out[b]       = sc[pa] - mx - logZ;
      out[192 + b] = mx + logZ - SS / S;
    }
    return;
  }
  {
    float* xs  = smem;
    float* red = smem + 1024;
    float* lg  = smem + 2048;
    float* r2  = smem + 2176;
    float* r3  = smem + 2192;
    int b = blk - 64;
    xs[tid] = sh[b*1024 + tid];
    __syncthreads();
    int n = tid & 127;
    int f0 = (tid >> 7) * 128;
    float acc = 0.f;
#pragma unroll 8
    for (int jj = 0; jj < 128; ++jj){
      int f = f0 + jj;
      acc = fmaf(xs[f], W2s[(size_t)f*ADIM + n], acc);
    }
    red[tid] = acc;
    __syncthreads();
    if (tid < 128){
      float s = b2s[tid];
#pragma unroll
      for (int jj = 0; jj < 8; ++jj) s += red[tid + jj*128];
      lg[tid] = s;
    }
    __syncthreads();
    float v = (tid < 128) ? lg[tid] : -1e30f;
    float mx = v;
    for (int off = 32; off; off >>= 1) mx = fmaxf(mx, __shfl_xor(mx, off));
    if ((tid & 63) == 0) r2[tid >> 6] = mx;
    __syncthreads();
    mx = -1e30f;
#pragma unroll
    for (int jj = 0; jj < 16; ++jj) mx = fmaxf(mx, r2[jj]);
    float e = (tid < 128) ? expf(v - mx) : 0.f;
    float se = e, ses = (tid < 128) ? e * v : 0.f;
    for (int off = 32; off; off >>= 1){ se += __shfl_xor(se, off); ses += __shfl_xor(ses, off); }
    __syncthreads();
    if ((tid & 63) == 0){ r2[tid >> 6] = se; r3[tid >> 6] = ses; }
    __syncthreads();
    if (tid == 0){
      float S = 0.f, SS = 0.f;
#pragma unroll
      for (int jj = 0; jj < 16; ++jj){ S += r2[jj]; SS += r3[jj]; }
      float logZ = logf(S);
      out[64 + b]  = lg[sym_action[b]] - mx - logZ;
      out[256 + b] = mx + logZ - SS / S;
    }
  }
}

extern "C" void kernel_launch(void* const* d_in, const int* in_sizes, int n_in,
                              void* d_out, int out_size, void* d_ws, size_t ws_size,
                              hipStream_t stream){
  const float* states = (const float*)d_in[0];
  const float* cls    = (const float*)d_in[1];
  const float* W1p    = (const float*)d_in[2];
  const float* b1p    = (const float*)d_in[3];
  const float* w2p    = (const float*)d_in[4];
  const float* W1s    = (const float*)d_in[6];
  const float* b1s    = (const float*)d_in[7];
  const float* W2s    = (const float*)d_in[8];
  const float* b2s    = (const float*)d_in[9];
  const float* Wc1    = (const float*)d_in[10];
  const float* bc1    = (const float*)d_in[11];
  const float* wc2    = (const float*)d_in[12];
  const float* bc2    = (const float*)d_in[13];
  const int* lengths  = (const int*)d_in[14];
  const int* pos_a    = (const int*)d_in[15];
  const int* sym_a    = (const int*)d_in[16];
  float* out = (float*)d_out;

  char* ws = (char*)d_ws;
  u16* sbf      = (u16*)ws;                      // 67108864 B (states bf16)
  u16* wt       = (u16*)(ws + 67108864);         //  2097152 B (W1p^T bf16)
  float* scores = (float*)(ws + 69206016);       //   262144 B (compact scores)
  float* sh     = (float*)(ws + 69468160);       //   262144 B (sym hidden)
  int* rows     = (int*)(ws + 69730304);         //   262144 B (compact row -> b*1024+s)
  int* aux      = (int*)(ws + 69992448);         //      320 B (cum[65], [70]=total, [71]=ntiles)

  k_prep<<<1601, 1024, 0, stream>>>(states, cls, W1p, W1s, b1s, Wc1, bc1, wc2, bc2,
                                    lengths, pos_a, sbf, wt, sh, rows, aux, scores, out);
  k_gemm_scores<<<4096, 256, 0, stream>>>(sbf, wt, b1p, w2p, rows, aux, scores);
  k_post<<<128, 1024, 0, stream>>>(scores, sh, W2s, b2s, aux, lengths, pos_a, sym_a, out);
}